// Round 14
// baseline (375.109 us; speedup 1.0000x reference)
//
#include <hip/hip_runtime.h>
#include <math.h>

#define NA 50000
#define NE 800000
#define FDIM 128
#define KDIM 64
#define NRI 3
#define NRA 2
#define NWAVES 5000
#define EPW 160    // NE / NWAVES, exact

typedef unsigned short ushort_t;
typedef unsigned int uint_t;
typedef __attribute__((ext_vector_type(8))) short short8v;
typedef __attribute__((ext_vector_type(4))) float f32x4;
typedef __attribute__((ext_vector_type(4))) unsigned short u16x4;

// DPP helpers (row = 16 lanes). rocPRIM convention: row_shr:d -> lane i reads i-d.
#define DPP_SHR1 0x111
#define DPP_SHR2 0x112
#define DPP_SHR4 0x114
#define DPP_SHR8 0x118
#define DPP_SHL1 0x101
template<int CTRL>
__device__ __forceinline__ int dpp_i(int x) {
    return __builtin_amdgcn_update_dpp(0, x, CTRL, 0xF, 0xF, true);
}
template<int CTRL>
__device__ __forceinline__ float dpp_f(float x) {
    return __int_as_float(dpp_i<CTRL>(__float_as_int(x)));
}

__device__ __forceinline__ float ssp_f(float x) {
    float e = __expf(-fabsf(x));
    return fmaxf(x, 0.0f) + __logf(1.0f + e) - 0.69314718055994530942f;
}
__device__ __forceinline__ ushort_t f2bf(float x) {
    unsigned u = __float_as_uint(x);
    u += 0x7FFFu + ((u >> 16) & 1u);          // RNE
    return (ushort_t)(u >> 16);
}
__device__ __forceinline__ float bf2f(ushort_t h) {
    return __uint_as_float(((unsigned)h) << 16);
}
__device__ __forceinline__ f32x4 ssp4(f32x4 v) {
    f32x4 r;
    #pragma unroll
    for (int j = 0; j < 4; ++j) r[j] = ssp_f(v[j]);
    return r;
}
__device__ __forceinline__ u16x4 pack4(f32x4 v) {
    u16x4 p;
    #pragma unroll
    for (int j = 0; j < 4; ++j) p[j] = f2bf(v[j]);
    return p;
}

// ---------------------------------------------------------------------------
// Weight pre-convert (once): fp32 -> bf16 into ws.
// wbf layout (ushort offsets): Wdesc@0 (8192), Wi@8192, Wj@24576,
// chain@40960: [Wri1_0,Wri2_0,Wri1_1,Wri2_1,Wri1_2,Wri2_2,Wd,Wra1_0,Wra2_0,Wra1_1,Wra2_1]
// ---------------------------------------------------------------------------
__global__ __launch_bounds__(256) void k_wconv(
    const float* __restrict__ Wdesc, const float* __restrict__ Wi,
    const float* __restrict__ Wj,    const float* __restrict__ Wri1,
    const float* __restrict__ Wri2,  const float* __restrict__ Wd,
    const float* __restrict__ Wra1,  const float* __restrict__ Wra2,
    ushort_t* __restrict__ wbf)
{
    const int seg = blockIdx.y;
    const int idx = blockIdx.x * 2048 + threadIdx.x * 8;
    const float* s; ushort_t* d; int cnt;
    const int CH = 40960;
    switch (seg) {
    case 0: cnt = 8192;  if (idx >= cnt) return; s = Wdesc + idx; d = wbf + idx; break;
    case 1: cnt = 16384; if (idx >= cnt) return; s = Wi + idx;    d = wbf + 8192 + idx; break;
    case 2: cnt = 16384; if (idx >= cnt) return; s = Wj + idx;    d = wbf + 24576 + idx; break;
    case 3: { cnt = 3*16384; if (idx >= cnt) return; int k = idx/16384, o = idx - k*16384;
              s = Wri1 + idx; d = wbf + CH + (2*k)*16384 + o; break; }
    case 4: { cnt = 3*16384; if (idx >= cnt) return; int k = idx/16384, o = idx - k*16384;
              s = Wri2 + idx; d = wbf + CH + (2*k+1)*16384 + o; break; }
    case 5: cnt = 16384; if (idx >= cnt) return; s = Wd + idx; d = wbf + CH + 6*16384 + idx; break;
    case 6: { cnt = 2*16384; if (idx >= cnt) return; int k = idx/16384, o = idx - k*16384;
              s = Wra1 + idx; d = wbf + CH + (7+2*k)*16384 + o; break; }
    default:{ cnt = 2*16384; if (idx >= cnt) return; int k = idx/16384, o = idx - k*16384;
              s = Wra2 + idx; d = wbf + CH + (8+2*k)*16384 + o; break; }
    }
    #pragma unroll
    for (int j = 0; j < 8; ++j) d[j] = f2bf(s[j]);
}

// ---------------------------------------------------------------------------
// Per-atom segment starts: row_start[i] = lower_bound(idx_i, i); row_start[NA]=NE
// ---------------------------------------------------------------------------
__global__ __launch_bounds__(256) void k_row_starts(
    const int* __restrict__ idx_i, int* __restrict__ row_start)
{
    int i = blockIdx.x * 256 + threadIdx.x;
    if (i > NA) return;
    if (i == NA) { row_start[NA] = NE; return; }
    int lo = 0, hi = NE;
    while (lo < hi) { int mid = (lo + hi) >> 1; if (idx_i[mid] < i) lo = mid + 1; else hi = mid; }
    row_start[i] = lo;
}

// ---------------------------------------------------------------------------
// Transposed-GEMM helpers (node kernels). Wave w owns atoms {16w + lrow}.
// ---------------------------------------------------------------------------
__device__ __forceinline__ void stage_w(const ushort_t* __restrict__ src,
                                        ushort_t (*wlds)[136], int t)
{
    const int r = t >> 1, c0 = (t & 1) * 64;
    const short8v* s = (const short8v*)(src + (size_t)r * FDIM + c0);
    #pragma unroll
    for (int q = 0; q < 8; ++q)
        *(short8v*)&wlds[r][c0 + q * 8] = s[q];
}

__device__ __forceinline__ void gemm_tile_T(
    const ushort_t (*actA)[136], const ushort_t (*wlds)[136],
    int w, int lrow, int kgrp, const float* __restrict__ bias, f32x4 acc[8])
{
    short8v bfr[4];
    #pragma unroll
    for (int ks = 0; ks < 4; ++ks)
        bfr[ks] = *(const short8v*)&actA[16 * w + lrow][ks * 32 + kgrp * 8];
    #pragma unroll
    for (int nf = 0; nf < 8; ++nf)
        acc[nf] = *(const f32x4*)(bias + 16 * nf + 4 * kgrp);
    #pragma unroll
    for (int nf = 0; nf < 8; ++nf)
        #pragma unroll
        for (int ks = 0; ks < 4; ++ks) {
            short8v av = *(const short8v*)&wlds[16 * nf + lrow][ks * 32 + kgrp * 8];
            acc[nf] = __builtin_amdgcn_mfma_f32_16x16x32_bf16(av, bfr[ks], acc[nf], 0, 0, 0);
        }
}

__device__ __forceinline__ void write_act_T(
    ushort_t (*actA)[136], int w, int lrow, int kgrp, const f32x4 v[8])
{
    #pragma unroll
    for (int nf = 0; nf < 8; ++nf)
        *(u16x4*)&actA[16 * w + lrow][16 * nf + 4 * kgrp] = pack4(ssp4(v[nf]));
}

// ---------------------------------------------------------------------------
// Node pre (MFMA, transposed): xi -> msg (f32), xja -> bf16
// ---------------------------------------------------------------------------
__global__ __launch_bounds__(256) void k_node_pre(
    const float* __restrict__ feat, const ushort_t* __restrict__ wbf,
    const float* __restrict__ bi, const float* __restrict__ bj,
    float* __restrict__ xi_out, ushort_t* __restrict__ xja_out)
{
    __shared__ ushort_t actA[64][136];
    __shared__ ushort_t wlds[128][136];
    const int t = threadIdx.x, lane = t & 63, w = t >> 6;
    const int lrow = lane & 15, kgrp = lane >> 4;
    const int atom = blockIdx.x * 64 + 16 * w + lrow;
    const bool ok = atom < NA;

    f32x4 v[8];
    #pragma unroll
    for (int nf = 0; nf < 8; ++nf)
        v[nf] = ok ? *(const f32x4*)(feat + (size_t)atom * FDIM + 16 * nf + 4 * kgrp)
                   : (f32x4){0.f, 0.f, 0.f, 0.f};
    write_act_T(actA, w, lrow, kgrp, v);
    __syncthreads();
    stage_w(wbf + 8192, wlds, t);
    __syncthreads();
    f32x4 acc[8];
    gemm_tile_T(actA, wlds, w, lrow, kgrp, bi, acc);
    if (ok)
        #pragma unroll
        for (int nf = 0; nf < 8; ++nf)
            *(f32x4*)(xi_out + (size_t)atom * FDIM + 16 * nf + 4 * kgrp) = ssp4(acc[nf]);
    __syncthreads();
    stage_w(wbf + 24576, wlds, t);
    __syncthreads();
    gemm_tile_T(actA, wlds, w, lrow, kgrp, bj, acc);
    if (ok)
        #pragma unroll
        for (int nf = 0; nf < 8; ++nf)
            *(u16x4*)(xja_out + (size_t)atom * FDIM + 16 * nf + 4 * kgrp) = pack4(ssp4(acc[nf]));
}

// ---------------------------------------------------------------------------
// Edge kernel, barrier/LDS/atomic-free. Wave g owns the segment-aligned edge
// range covering targets [g*EPW, (g+1)*EPW) (merge-path on row_start), so each
// ATOM belongs to exactly one wave -> plain RMW of msg, bit-deterministic.
// Per 16-edge tile: MFMA p = desc@Wdesc^T (C frag: edge = lane&15 within each
// DPP row), gather-mul by xja[idx_j], 4-step DPP segmented inclusive scan
// over edges, fragment-end lanes RMW msg[sid] += fragment sum.
// ---------------------------------------------------------------------------
__device__ __forceinline__ short8v pack8(const float* p) {
    short8v r;
    #pragma unroll
    for (int j = 0; j < 8; ++j) r[j] = (short)f2bf(p[j]);
    return r;
}

__global__ __launch_bounds__(256) void k_edge_scan(
    const float* __restrict__ desc, const ushort_t* __restrict__ wdbf,
    const int* __restrict__ row_start,
    const int* __restrict__ idx_i, const int* __restrict__ idx_j,
    const ushort_t* __restrict__ xja,
    float* __restrict__ msg)
{
    const int t = threadIdx.x, lane = t & 63;
    const int g = blockIdx.x * 4 + (t >> 6);
    const int lrow = lane & 15, kgrp = lane >> 4;

    // merge-path: atoms [a_lo, a_hi), edges [row_start[a_lo], row_start[a_hi])
    const int tgt_lo = g * EPW, tgt_hi = tgt_lo + EPW;
    int lo = 0, hi = NA + 1;
    while (lo < hi) { int mid = (lo + hi) >> 1; if (row_start[mid] < tgt_lo) lo = mid + 1; else hi = mid; }
    const int a_lo = lo;
    hi = NA + 1;
    while (lo < hi) { int mid = (lo + hi) >> 1; if (row_start[mid] < tgt_hi) lo = mid + 1; else hi = mid; }
    const int a_hi = lo;
    const int s = row_start[a_lo];
    const int e = row_start[a_hi];
    if (s >= e) return;

    // Wdesc A-fragments, once per wave (L2-hot bf16)
    short8v wf[8][2];
    #pragma unroll
    for (int nf = 0; nf < 8; ++nf)
        #pragma unroll
        for (int ks = 0; ks < 2; ++ks)
            wf[nf][ks] = *(const short8v*)(wdbf + (size_t)(16 * nf + lrow) * KDIM
                                           + ks * 32 + kgrp * 8);

    for (int base = s; base < e; base += 16) {
        const int er = base + lrow;
        const bool act = er < e;
        int sid = -1, jj = 0;
        short8v b0, b1;
        if (act) {
            sid = idx_i[er];
            jj  = idx_j[er];
            const float* q = desc + (size_t)er * KDIM + kgrp * 8;
            float t0[8], t1[8];
            *(float4*)(t0)     = *(const float4*)q;
            *(float4*)(t0 + 4) = *(const float4*)(q + 4);
            *(float4*)(t1)     = *(const float4*)(q + 32);
            *(float4*)(t1 + 4) = *(const float4*)(q + 36);
            b0 = pack8(t0); b1 = pack8(t1);
        } else {
            b0 = (short8v){0,0,0,0,0,0,0,0};
            b1 = b0;
        }
        const int sp1 = sid + 1;   // 0 for inactive lanes

        f32x4 acc[8];
        #pragma unroll
        for (int nf = 0; nf < 8; ++nf) acc[nf] = (f32x4){0.f, 0.f, 0.f, 0.f};
        #pragma unroll
        for (int nf = 0; nf < 8; ++nf) {
            acc[nf] = __builtin_amdgcn_mfma_f32_16x16x32_bf16(wf[nf][0], b0, acc[nf], 0,0,0);
            acc[nf] = __builtin_amdgcn_mfma_f32_16x16x32_bf16(wf[nf][1], b1, acc[nf], 0,0,0);
        }

        // p = acc * xja[idx_j]  (stays f32 in registers)
        float v[8][4];
        if (act) {
            #pragma unroll
            for (int nf = 0; nf < 8; ++nf) {
                u16x4 xv = *(const u16x4*)(xja + (size_t)jj * FDIM + 16 * nf + 4 * kgrp);
                #pragma unroll
                for (int j = 0; j < 4; ++j) v[nf][j] = acc[nf][j] * bf2f(xv[j]);
            }
        } else {
            #pragma unroll
            for (int nf = 0; nf < 8; ++nf)
                #pragma unroll
                for (int j = 0; j < 4; ++j) v[nf][j] = 0.0f;
        }

        // segmented inclusive scan over the 16 edges of this DPP row
        const float m1 = (sp1 == dpp_i<DPP_SHR1>(sp1)) ? 1.0f : 0.0f;
        const float m2 = (sp1 == dpp_i<DPP_SHR2>(sp1)) ? 1.0f : 0.0f;
        const float m4 = (sp1 == dpp_i<DPP_SHR4>(sp1)) ? 1.0f : 0.0f;
        const float m8 = (sp1 == dpp_i<DPP_SHR8>(sp1)) ? 1.0f : 0.0f;
        #pragma unroll
        for (int nf = 0; nf < 8; ++nf)
            #pragma unroll
            for (int j = 0; j < 4; ++j) {
                float x = v[nf][j];
                x = fmaf(m1, dpp_f<DPP_SHR1>(x), x);
                x = fmaf(m2, dpp_f<DPP_SHR2>(x), x);
                x = fmaf(m4, dpp_f<DPP_SHR4>(x), x);
                x = fmaf(m8, dpp_f<DPP_SHR8>(x), x);
                v[nf][j] = x;
            }

        // fragment-end lanes flush: plain float4 RMW (wave owns these atoms)
        const int nsp1 = dpp_i<DPP_SHL1>(sp1);   // lane l <- sp1[l+1], lane15 <- 0
        if (sp1 != 0 && sp1 != nsp1) {
            float* mrow = msg + (size_t)(sp1 - 1) * FDIM + 4 * kgrp;
            #pragma unroll
            for (int nf = 0; nf < 8; ++nf) {
                float4* p4 = (float4*)(mrow + 16 * nf);
                float4 mv = *p4;
                mv.x += v[nf][0]; mv.y += v[nf][1];
                mv.z += v[nf][2]; mv.w += v[nf][3];
                *p4 = mv;
            }
        }
    }
}

// ---------------------------------------------------------------------------
// Fused node chain (transposed): 3 residuals + outmix + 2 residuals.
// ---------------------------------------------------------------------------
__global__ __launch_bounds__(256) void k_chain(
    const float* __restrict__ msgp, const float* __restrict__ feat,
    const float* __restrict__ u, const ushort_t* __restrict__ wch,
    const float* __restrict__ bri1, const float* __restrict__ bri2,
    const float* __restrict__ bd,
    const float* __restrict__ bra1, const float* __restrict__ bra2,
    float* __restrict__ xout)
{
    __shared__ ushort_t actA[64][136];
    __shared__ ushort_t wlds[128][136];
    const int t = threadIdx.x, lane = t & 63, w = t >> 6;
    const int lrow = lane & 15, kgrp = lane >> 4;
    const int atom = blockIdx.x * 64 + 16 * w + lrow;
    const bool ok = atom < NA;

    f32x4 m[8], h[8], acc[8];
    #pragma unroll
    for (int nf = 0; nf < 8; ++nf)
        m[nf] = ok ? *(const f32x4*)(msgp + (size_t)atom * FDIM + 16 * nf + 4 * kgrp)
                   : (f32x4){0.f, 0.f, 0.f, 0.f};

    for (int k = 0; k < NRI; ++k) {
        write_act_T(actA, w, lrow, kgrp, m);
        __syncthreads();
        stage_w(wch + (size_t)(2 * k) * 16384, wlds, t);
        __syncthreads();
        gemm_tile_T(actA, wlds, w, lrow, kgrp, bri1 + k * FDIM, acc);
        #pragma unroll
        for (int nf = 0; nf < 8; ++nf) h[nf] = acc[nf];
        write_act_T(actA, w, lrow, kgrp, h);
        __syncthreads();
        stage_w(wch + (size_t)(2 * k + 1) * 16384, wlds, t);
        __syncthreads();
        gemm_tile_T(actA, wlds, w, lrow, kgrp, bri2 + k * FDIM, acc);
        #pragma unroll
        for (int nf = 0; nf < 8; ++nf) m[nf] += acc[nf];
    }

    write_act_T(actA, w, lrow, kgrp, m);
    __syncthreads();
    stage_w(wch + (size_t)6 * 16384, wlds, t);
    __syncthreads();
    gemm_tile_T(actA, wlds, w, lrow, kgrp, bd, acc);
    #pragma unroll
    for (int nf = 0; nf < 8; ++nf) {
        f32x4 fv = ok ? *(const f32x4*)(feat + (size_t)atom * FDIM + 16 * nf + 4 * kgrp)
                      : (f32x4){0.f, 0.f, 0.f, 0.f};
        f32x4 uv = *(const f32x4*)(u + 16 * nf + 4 * kgrp);
        m[nf] = uv * fv + acc[nf];
    }

    for (int k = 0; k < NRA; ++k) {
        write_act_T(actA, w, lrow, kgrp, m);
        __syncthreads();
        stage_w(wch + (size_t)(7 + 2 * k) * 16384, wlds, t);
        __syncthreads();
        gemm_tile_T(actA, wlds, w, lrow, kgrp, bra1 + k * FDIM, acc);
        #pragma unroll
        for (int nf = 0; nf < 8; ++nf) h[nf] = acc[nf];
        write_act_T(actA, w, lrow, kgrp, h);
        __syncthreads();
        stage_w(wch + (size_t)(8 + 2 * k) * 16384, wlds, t);
        __syncthreads();
        gemm_tile_T(actA, wlds, w, lrow, kgrp, bra2 + k * FDIM, acc);
        #pragma unroll
        for (int nf = 0; nf < 8; ++nf) m[nf] += acc[nf];
    }

    if (ok)
        #pragma unroll
        for (int nf = 0; nf < 8; ++nf)
            *(f32x4*)(xout + (size_t)atom * FDIM + 16 * nf + 4 * kgrp) = m[nf];
}

// ---------------------------------------------------------------------------
extern "C" void kernel_launch(void* const* d_in, const int* in_sizes, int n_in,
                              void* d_out, int out_size, void* d_ws, size_t ws_size,
                              hipStream_t stream)
{
    const float* feat  = (const float*)d_in[0];
    const float* desc  = (const float*)d_in[1];
    const int*   idx_i = (const int*)d_in[2];
    const int*   idx_j = (const int*)d_in[3];
    const float* Wdesc = (const float*)d_in[4];
    const float* Wi    = (const float*)d_in[5];
    const float* bi    = (const float*)d_in[6];
    const float* Wj    = (const float*)d_in[7];
    const float* bj    = (const float*)d_in[8];
    const float* Wri1  = (const float*)d_in[9];
    const float* bri1  = (const float*)d_in[10];
    const float* Wri2  = (const float*)d_in[11];
    const float* bri2  = (const float*)d_in[12];
    const float* Wd    = (const float*)d_in[13];
    const float* bd    = (const float*)d_in[14];
    const float* u     = (const float*)d_in[15];
    const float* Wra1  = (const float*)d_in[16];
    const float* bra1  = (const float*)d_in[17];
    const float* Wra2  = (const float*)d_in[18];
    const float* bra2  = (const float*)d_in[19];

    char* wsp = (char*)d_ws;
    float* msg = (float*)wsp;                             // NA*F f32
    size_t off = (size_t)NA * FDIM * sizeof(float);
    ushort_t* xja = (ushort_t*)(wsp + off);               // NA*F bf16
    off += (size_t)NA * FDIM * sizeof(ushort_t);
    int* row_start = (int*)(wsp + off);                   // NA+1 ints
    off += (((size_t)(NA + 1) * sizeof(int)) + 255) & ~(size_t)255;
    ushort_t* wbf = (ushort_t*)(wsp + off);               // bf16 weights
    off += (((size_t)221184 * sizeof(ushort_t)) + 255) & ~(size_t)255;

    float* xout = (float*)d_out;
    const int nblk64 = (NA + 63) / 64;

    k_wconv<<<dim3(24, 8), 256, 0, stream>>>(Wdesc, Wi, Wj, Wri1, Wri2, Wd, Wra1, Wra2, wbf);
    k_row_starts<<<(NA + 256) / 256, 256, 0, stream>>>(idx_i, row_start);
    k_node_pre<<<nblk64, 256, 0, stream>>>(feat, wbf, bi, bj, msg, xja);
    k_edge_scan<<<NWAVES / 4, 256, 0, stream>>>(desc, wbf, row_start, idx_i, idx_j, xja, msg);
    k_chain<<<nblk64, 256, 0, stream>>>(msg, feat, u, wbf + 40960,
                                        bri1, bri2, bd, bra1, bra2, xout);
}

// Round 15
// 233.035 us; speedup vs baseline: 1.6097x; 1.6097x over previous
//
#include <hip/hip_runtime.h>
#include <math.h>

#define NA 50000
#define NE 800000
#define FDIM 128
#define KDIM 64
#define NRI 3
#define NRA 2
#define ETILES 10   // 64-edge tiles per block; NE / (64*ETILES) = 1250 exact

typedef unsigned short ushort_t;
typedef unsigned int uint_t;
typedef __attribute__((ext_vector_type(8))) short short8v;
typedef __attribute__((ext_vector_type(4))) float f32x4;
typedef __attribute__((ext_vector_type(4))) unsigned short u16x4;

// ssp(x) = softplus(x) - ln2 via hardware v_exp_f32/v_log_f32.
__device__ __forceinline__ float ssp_f(float x) {
    float e = __expf(-fabsf(x));
    return fmaxf(x, 0.0f) + __logf(1.0f + e) - 0.69314718055994530942f;
}
__device__ __forceinline__ ushort_t f2bf(float x) {
    unsigned u = __float_as_uint(x);
    u += 0x7FFFu + ((u >> 16) & 1u);          // RNE
    return (ushort_t)(u >> 16);
}
__device__ __forceinline__ float bf2f(ushort_t h) {
    return __uint_as_float(((unsigned)h) << 16);
}
__device__ __forceinline__ f32x4 ssp4(f32x4 v) {
    f32x4 r;
    #pragma unroll
    for (int j = 0; j < 4; ++j) r[j] = ssp_f(v[j]);
    return r;
}
__device__ __forceinline__ u16x4 pack4(f32x4 v) {
    u16x4 p;
    #pragma unroll
    for (int j = 0; j < 4; ++j) p[j] = f2bf(v[j]);
    return p;
}

// ---------------------------------------------------------------------------
// Weight pre-convert (once): fp32 -> bf16 into ws.
// wbf layout (ushort offsets): Wdesc@0 (8192), Wi@8192, Wj@24576,
// chain@40960: [Wri1_0,Wri2_0,Wri1_1,Wri2_1,Wri1_2,Wri2_2,Wd,Wra1_0,Wra2_0,Wra1_1,Wra2_1]
// ---------------------------------------------------------------------------
__global__ __launch_bounds__(256) void k_wconv(
    const float* __restrict__ Wdesc, const float* __restrict__ Wi,
    const float* __restrict__ Wj,    const float* __restrict__ Wri1,
    const float* __restrict__ Wri2,  const float* __restrict__ Wd,
    const float* __restrict__ Wra1,  const float* __restrict__ Wra2,
    ushort_t* __restrict__ wbf)
{
    const int seg = blockIdx.y;
    const int idx = blockIdx.x * 2048 + threadIdx.x * 8;
    const float* s; ushort_t* d; int cnt;
    const int CH = 40960;
    switch (seg) {
    case 0: cnt = 8192;  if (idx >= cnt) return; s = Wdesc + idx; d = wbf + idx; break;
    case 1: cnt = 16384; if (idx >= cnt) return; s = Wi + idx;    d = wbf + 8192 + idx; break;
    case 2: cnt = 16384; if (idx >= cnt) return; s = Wj + idx;    d = wbf + 24576 + idx; break;
    case 3: { cnt = 3*16384; if (idx >= cnt) return; int k = idx/16384, o = idx - k*16384;
              s = Wri1 + idx; d = wbf + CH + (2*k)*16384 + o; break; }
    case 4: { cnt = 3*16384; if (idx >= cnt) return; int k = idx/16384, o = idx - k*16384;
              s = Wri2 + idx; d = wbf + CH + (2*k+1)*16384 + o; break; }
    case 5: cnt = 16384; if (idx >= cnt) return; s = Wd + idx; d = wbf + CH + 6*16384 + idx; break;
    case 6: { cnt = 2*16384; if (idx >= cnt) return; int k = idx/16384, o = idx - k*16384;
              s = Wra1 + idx; d = wbf + CH + (7+2*k)*16384 + o; break; }
    default:{ cnt = 2*16384; if (idx >= cnt) return; int k = idx/16384, o = idx - k*16384;
              s = Wra2 + idx; d = wbf + CH + (8+2*k)*16384 + o; break; }
    }
    #pragma unroll
    for (int j = 0; j < 8; ++j) d[j] = f2bf(s[j]);
}

// ---------------------------------------------------------------------------
// Transposed-GEMM helpers. Wave w owns atoms {16w + lrow}; each lane holds
// features {16nf + 4kgrp + r} of its atom.
// ---------------------------------------------------------------------------
__device__ __forceinline__ void stage_w(const ushort_t* __restrict__ src,
                                        ushort_t (*wlds)[136], int t)
{
    const int r = t >> 1, c0 = (t & 1) * 64;
    const short8v* s = (const short8v*)(src + (size_t)r * FDIM + c0);
    #pragma unroll
    for (int q = 0; q < 8; ++q)
        *(short8v*)&wlds[r][c0 + q * 8] = s[q];
}

__device__ __forceinline__ void gemm_tile_T(
    const ushort_t (*actA)[136], const ushort_t (*wlds)[136],
    int w, int lrow, int kgrp, const float* __restrict__ bias, f32x4 acc[8])
{
    short8v bfr[4];
    #pragma unroll
    for (int ks = 0; ks < 4; ++ks)
        bfr[ks] = *(const short8v*)&actA[16 * w + lrow][ks * 32 + kgrp * 8];
    #pragma unroll
    for (int nf = 0; nf < 8; ++nf)
        acc[nf] = *(const f32x4*)(bias + 16 * nf + 4 * kgrp);
    #pragma unroll
    for (int nf = 0; nf < 8; ++nf)
        #pragma unroll
        for (int ks = 0; ks < 4; ++ks) {
            short8v av = *(const short8v*)&wlds[16 * nf + lrow][ks * 32 + kgrp * 8];
            acc[nf] = __builtin_amdgcn_mfma_f32_16x16x32_bf16(av, bfr[ks], acc[nf], 0, 0, 0);
        }
}

__device__ __forceinline__ void write_act_T(
    ushort_t (*actA)[136], int w, int lrow, int kgrp, const f32x4 v[8])
{
    #pragma unroll
    for (int nf = 0; nf < 8; ++nf)
        *(u16x4*)&actA[16 * w + lrow][16 * nf + 4 * kgrp] = pack4(ssp4(v[nf]));
}

// ---------------------------------------------------------------------------
// Node pre (MFMA, transposed): xi -> msg (f32), xja -> bf16
// ---------------------------------------------------------------------------
__global__ __launch_bounds__(256) void k_node_pre(
    const float* __restrict__ feat, const ushort_t* __restrict__ wbf,
    const float* __restrict__ bi, const float* __restrict__ bj,
    float* __restrict__ xi_out, ushort_t* __restrict__ xja_out)
{
    __shared__ ushort_t actA[64][136];
    __shared__ ushort_t wlds[128][136];
    const int t = threadIdx.x, lane = t & 63, w = t >> 6;
    const int lrow = lane & 15, kgrp = lane >> 4;
    const int atom = blockIdx.x * 64 + 16 * w + lrow;
    const bool ok = atom < NA;

    f32x4 v[8];
    #pragma unroll
    for (int nf = 0; nf < 8; ++nf)
        v[nf] = ok ? *(const f32x4*)(feat + (size_t)atom * FDIM + 16 * nf + 4 * kgrp)
                   : (f32x4){0.f, 0.f, 0.f, 0.f};
    write_act_T(actA, w, lrow, kgrp, v);
    __syncthreads();
    stage_w(wbf + 8192, wlds, t);
    __syncthreads();
    f32x4 acc[8];
    gemm_tile_T(actA, wlds, w, lrow, kgrp, bi, acc);
    if (ok)
        #pragma unroll
        for (int nf = 0; nf < 8; ++nf)
            *(f32x4*)(xi_out + (size_t)atom * FDIM + 16 * nf + 4 * kgrp) = ssp4(acc[nf]);
    __syncthreads();
    stage_w(wbf + 24576, wlds, t);
    __syncthreads();
    gemm_tile_T(actA, wlds, w, lrow, kgrp, bj, acc);
    if (ok)
        #pragma unroll
        for (int nf = 0; nf < 8; ++nf)
            *(u16x4*)(xja_out + (size_t)atom * FDIM + 16 * nf + 4 * kgrp) = pack4(ssp4(acc[nf]));
}

// ---------------------------------------------------------------------------
// Fused edge kernel (round-13 structure + DEPTH-2 desc prefetch):
//   p[e][f] = (desc[e]@Wdesc[f]) * xja[idx_j[e]][f]   (MFMA, bf16 in LDS)
// - pl/ii double-buffered, ONE barrier per tile
// - desc/idx_j prefetched TWO tiles ahead (HBM ~900cyc > 1 tile of work);
//   xja gather one tile ahead (L2/L3 latency); loop unrolled x2 so all
//   staging slots are compile-time registers.
// - segment carry (scur,sacc) across tiles; each p added exactly once.
// ---------------------------------------------------------------------------
__device__ __forceinline__ short8v pack8(const float* p) {
    short8v r;
    #pragma unroll
    for (int j = 0; j < 8; ++j) r[j] = (short)f2bf(p[j]);
    return r;
}

#define LOAD_DESC(T0, T1, ern)                                        \
    {                                                                 \
        const float* q_ = desc + (size_t)(ern) * KDIM + kgrp * 8;     \
        *(float4*)(T0)     = *(const float4*)q_;                      \
        *(float4*)(T0 + 4) = *(const float4*)(q_ + 4);                \
        *(float4*)(T1)     = *(const float4*)(q_ + 32);               \
        *(float4*)(T1 + 4) = *(const float4*)(q_ + 36);               \
    }

#define EDGE_TILE(T0, T1, JJCUR, JJOTH, BUF, TT)                              \
    {                                                                         \
        if (t < 64) ii[BUF][t] = idx_i[ebase + (TT) * 64 + t];                \
        short8v b0 = pack8(T0), b1 = pack8(T1);                               \
        f32x4 acc[8];                                                         \
        _Pragma("unroll")                                                     \
        for (int nf = 0; nf < 8; ++nf) acc[nf] = (f32x4){0.f,0.f,0.f,0.f};    \
        _Pragma("unroll")                                                     \
        for (int nf = 0; nf < 8; ++nf) {                                      \
            acc[nf] = __builtin_amdgcn_mfma_f32_16x16x32_bf16(a[nf][0], b0, acc[nf],0,0,0); \
            acc[nf] = __builtin_amdgcn_mfma_f32_16x16x32_bf16(a[nf][1], b1, acc[nf],0,0,0); \
        }                                                                     \
        _Pragma("unroll")                                                     \
        for (int nf = 0; nf < 8; ++nf) {                                      \
            f32x4 pr;                                                         \
            _Pragma("unroll")                                                 \
            for (int j = 0; j < 4; ++j) pr[j] = acc[nf][j] * bf2f(xv[nf][j]); \
            *(u16x4*)&pl[BUF][w * 16 + lrow][16 * nf + 4 * kgrp] = pack4(pr); \
        }                                                                     \
        if ((TT) + 2 < ETILES) {                                              \
            int ern_ = ebase + ((TT) + 2) * 64 + eoff;                        \
            JJCUR = idx_j[ern_];                                              \
            LOAD_DESC(T0, T1, ern_)                                           \
        }                                                                     \
        if ((TT) + 1 < ETILES) {                                              \
            _Pragma("unroll")                                                 \
            for (int nf = 0; nf < 8; ++nf)                                    \
                xv[nf] = *(const u16x4*)(xja + (size_t)(JJOTH) * FDIM + 16 * nf + 4 * kgrp); \
        }                                                                     \
        __syncthreads();                                                      \
        _Pragma("unroll")                                                     \
        for (int g = 0; g < 8; ++g) {                                         \
            float vv[4]; int id[4];                                           \
            _Pragma("unroll")                                                 \
            for (int qq = 0; qq < 4; ++qq) {                                  \
                vv[qq] = bf2f(pl[BUF][r0 + g * 4 + qq][f]);                   \
                id[qq] = ii[BUF][r0 + g * 4 + qq];                            \
            }                                                                 \
            _Pragma("unroll")                                                 \
            for (int qq = 0; qq < 4; ++qq) {                                  \
                if (id[qq] != scur) {                                         \
                    if (scur >= 0) unsafeAtomicAdd(&msg[(size_t)scur * FDIM + f], sacc); \
                    sacc = 0.0f; scur = id[qq];                               \
                }                                                             \
                sacc += vv[qq];                                               \
            }                                                                 \
        }                                                                     \
    }

__global__ __launch_bounds__(256) void k_edge_fused(
    const float* __restrict__ desc, const ushort_t* __restrict__ wdbf,
    const int* __restrict__ idx_i, const int* __restrict__ idx_j,
    const ushort_t* __restrict__ xja,
    float* __restrict__ msg)
{
    __shared__ ushort_t pl[2][64][136];   // 34.8 KB (double-buffered)
    __shared__ int ii[2][64];
    const int t = threadIdx.x, lane = t & 63, w = t >> 6;
    const int lrow = lane & 15, kgrp = lane >> 4;
    const int ebase = blockIdx.x * (64 * ETILES);
    const int eoff = w * 16 + lrow;

    // Wdesc A-fragments: once per block
    short8v a[8][2];
    #pragma unroll
    for (int nf = 0; nf < 8; ++nf)
        #pragma unroll
        for (int ks = 0; ks < 2; ++ks)
            a[nf][ks] = *(const short8v*)(wdbf + (size_t)(16 * nf + lrow) * KDIM
                                          + ks * 32 + kgrp * 8);

    // depth-2 prologue: desc/jj for tiles 0 and 1, gather for tile 0
    float tA0[8], tA1[8], tB0[8], tB1[8];
    int jjA = idx_j[ebase + eoff];
    LOAD_DESC(tA0, tA1, ebase + eoff)
    int jjB = idx_j[ebase + 64 + eoff];
    LOAD_DESC(tB0, tB1, ebase + 64 + eoff)
    u16x4 xv[8];
    #pragma unroll
    for (int nf = 0; nf < 8; ++nf)
        xv[nf] = *(const u16x4*)(xja + (size_t)jjA * FDIM + 16 * nf + 4 * kgrp);

    // flush carry (persists across tiles)
    const int f = t & 127, h = t >> 7;
    const int r0 = h * 32;
    float sacc = 0.0f;
    int scur = -1;

    for (int tt = 0; tt < ETILES; tt += 2) {
        EDGE_TILE(tA0, tA1, jjA, jjB, 0, tt)
        EDGE_TILE(tB0, tB1, jjB, jjA, 1, tt + 1)
    }
    if (scur >= 0) unsafeAtomicAdd(&msg[(size_t)scur * FDIM + f], sacc);
}

// ---------------------------------------------------------------------------
// Fused node chain (transposed): 3 residuals + outmix + 2 residuals.
// ---------------------------------------------------------------------------
__global__ __launch_bounds__(256) void k_chain(
    const float* __restrict__ msgp, const float* __restrict__ feat,
    const float* __restrict__ u, const ushort_t* __restrict__ wch,
    const float* __restrict__ bri1, const float* __restrict__ bri2,
    const float* __restrict__ bd,
    const float* __restrict__ bra1, const float* __restrict__ bra2,
    float* __restrict__ xout)
{
    __shared__ ushort_t actA[64][136];
    __shared__ ushort_t wlds[128][136];
    const int t = threadIdx.x, lane = t & 63, w = t >> 6;
    const int lrow = lane & 15, kgrp = lane >> 4;
    const int atom = blockIdx.x * 64 + 16 * w + lrow;
    const bool ok = atom < NA;

    f32x4 m[8], h[8], acc[8];
    #pragma unroll
    for (int nf = 0; nf < 8; ++nf)
        m[nf] = ok ? *(const f32x4*)(msgp + (size_t)atom * FDIM + 16 * nf + 4 * kgrp)
                   : (f32x4){0.f, 0.f, 0.f, 0.f};

    for (int k = 0; k < NRI; ++k) {
        write_act_T(actA, w, lrow, kgrp, m);
        __syncthreads();
        stage_w(wch + (size_t)(2 * k) * 16384, wlds, t);
        __syncthreads();
        gemm_tile_T(actA, wlds, w, lrow, kgrp, bri1 + k * FDIM, acc);
        #pragma unroll
        for (int nf = 0; nf < 8; ++nf) h[nf] = acc[nf];
        write_act_T(actA, w, lrow, kgrp, h);
        __syncthreads();
        stage_w(wch + (size_t)(2 * k + 1) * 16384, wlds, t);
        __syncthreads();
        gemm_tile_T(actA, wlds, w, lrow, kgrp, bri2 + k * FDIM, acc);
        #pragma unroll
        for (int nf = 0; nf < 8; ++nf) m[nf] += acc[nf];
    }

    write_act_T(actA, w, lrow, kgrp, m);
    __syncthreads();
    stage_w(wch + (size_t)6 * 16384, wlds, t);
    __syncthreads();
    gemm_tile_T(actA, wlds, w, lrow, kgrp, bd, acc);
    #pragma unroll
    for (int nf = 0; nf < 8; ++nf) {
        f32x4 fv = ok ? *(const f32x4*)(feat + (size_t)atom * FDIM + 16 * nf + 4 * kgrp)
                      : (f32x4){0.f, 0.f, 0.f, 0.f};
        f32x4 uv = *(const f32x4*)(u + 16 * nf + 4 * kgrp);
        m[nf] = uv * fv + acc[nf];
    }

    for (int k = 0; k < NRA; ++k) {
        write_act_T(actA, w, lrow, kgrp, m);
        __syncthreads();
        stage_w(wch + (size_t)(7 + 2 * k) * 16384, wlds, t);
        __syncthreads();
        gemm_tile_T(actA, wlds, w, lrow, kgrp, bra1 + k * FDIM, acc);
        #pragma unroll
        for (int nf = 0; nf < 8; ++nf) h[nf] = acc[nf];
        write_act_T(actA, w, lrow, kgrp, h);
        __syncthreads();
        stage_w(wch + (size_t)(8 + 2 * k) * 16384, wlds, t);
        __syncthreads();
        gemm_tile_T(actA, wlds, w, lrow, kgrp, bra2 + k * FDIM, acc);
        #pragma unroll
        for (int nf = 0; nf < 8; ++nf) m[nf] += acc[nf];
    }

    if (ok)
        #pragma unroll
        for (int nf = 0; nf < 8; ++nf)
            *(f32x4*)(xout + (size_t)atom * FDIM + 16 * nf + 4 * kgrp) = m[nf];
}

// ---------------------------------------------------------------------------
extern "C" void kernel_launch(void* const* d_in, const int* in_sizes, int n_in,
                              void* d_out, int out_size, void* d_ws, size_t ws_size,
                              hipStream_t stream)
{
    const float* feat  = (const float*)d_in[0];
    const float* desc  = (const float*)d_in[1];
    const int*   idx_i = (const int*)d_in[2];
    const int*   idx_j = (const int*)d_in[3];
    const float* Wdesc = (const float*)d_in[4];
    const float* Wi    = (const float*)d_in[5];
    const float* bi    = (const float*)d_in[6];
    const float* Wj    = (const float*)d_in[7];
    const float* bj    = (const float*)d_in[8];
    const float* Wri1  = (const float*)d_in[9];
    const float* bri1  = (const float*)d_in[10];
    const float* Wri2  = (const float*)d_in[11];
    const float* bri2  = (const float*)d_in[12];
    const float* Wd    = (const float*)d_in[13];
    const float* bd    = (const float*)d_in[14];
    const float* u     = (const float*)d_in[15];
    const float* Wra1  = (const float*)d_in[16];
    const float* bra1  = (const float*)d_in[17];
    const float* Wra2  = (const float*)d_in[18];
    const float* bra2  = (const float*)d_in[19];

    char* wsp = (char*)d_ws;
    float* msg = (float*)wsp;                             // NA*F f32
    size_t off = (size_t)NA * FDIM * sizeof(float);
    ushort_t* xja = (ushort_t*)(wsp + off);               // NA*F bf16
    off += (size_t)NA * FDIM * sizeof(ushort_t);
    ushort_t* wbf = (ushort_t*)(wsp + off);               // bf16 weights
    off += (((size_t)221184 * sizeof(ushort_t)) + 255) & ~(size_t)255;

    float* xout = (float*)d_out;
    const int nblk64 = (NA + 63) / 64;

    k_wconv<<<dim3(24, 8), 256, 0, stream>>>(Wdesc, Wi, Wj, Wri1, Wri2, Wd, Wra1, Wra2, wbf);
    k_node_pre<<<nblk64, 256, 0, stream>>>(feat, wbf, bi, bj, msg, xja);
    k_edge_fused<<<NE / (64 * ETILES), 256, 0, stream>>>(desc, wbf, idx_i, idx_j, xja, msg);
    k_chain<<<nblk64, 256, 0, stream>>>(msg, feat, u, wbf + 40960,
                                        bri1, bri2, bd, bra1, bra2, xout);
}